// Round 3
// baseline (662.866 us; speedup 1.0000x reference)
//
#include <hip/hip_runtime.h>
#include <math.h>

// -------------------- wave helpers --------------------
__device__ __forceinline__ float wave_sum(float x) {
#pragma unroll
  for (int off = 32; off > 0; off >>= 1) x += __shfl_xor(x, off, 64);
  return x;
}

// -------------------- edge prep --------------------
__global__ void count_kernel(const int* __restrict__ eic, const int* __restrict__ eiv,
                             int* __restrict__ cnt_c, int* __restrict__ cnt_v, int E) {
  int i = blockIdx.x * blockDim.x + threadIdx.x;
  if (i < E) {
    atomicAdd(&cnt_c[eic[E + i]], 1);
    atomicAdd(&cnt_v[eiv[E + i]], 1);
  }
}

// one block per relation (grid=2, block=1024): exclusive scan of counts
__global__ void scan_kernel(const int* __restrict__ cnt_c, int* __restrict__ row_c, int* __restrict__ cur_c,
                            const int* __restrict__ cnt_v, int* __restrict__ row_v, int* __restrict__ cur_v,
                            int n) {
  const int* cnt = blockIdx.x ? cnt_v : cnt_c;
  int* row = blockIdx.x ? row_v : row_c;
  int* cur = blockIdx.x ? cur_v : cur_c;
  __shared__ int wsum[16];
  __shared__ int stot;
  const int tid = threadIdx.x;
  const int lane = tid & 63, wid = tid >> 6;
  int carry = 0;
  for (int base = 0; base < n; base += 1024) {
    int i = base + tid;
    int v = (i < n) ? cnt[i] : 0;
    int x = v;
#pragma unroll
    for (int off = 1; off < 64; off <<= 1) {
      int y = __shfl_up(x, off, 64);
      if (lane >= off) x += y;
    }
    if (lane == 63) wsum[wid] = x;
    __syncthreads();
    if (tid == 0) {
      int s = 0;
#pragma unroll
      for (int w = 0; w < 16; ++w) { int t = wsum[w]; wsum[w] = s; s += t; }
      stot = s;
    }
    __syncthreads();
    int excl = carry + wsum[wid] + (x - v);
    if (i < n) { row[i] = excl; cur[i] = excl; }
    carry += stot;
    __syncthreads();
  }
}

__global__ void dis_kernel(const int* __restrict__ cnt_c, const int* __restrict__ cnt_v,
                           float* __restrict__ dis_c, float* __restrict__ dis_v,
                           float* __restrict__ dis_cb, int n) {
  int i = blockIdx.x * blockDim.x + threadIdx.x;
  if (i < n) {
    int cc = cnt_c[i], cv = cnt_v[i];
    dis_c[i]  = rsqrtf((float)(cc + 1));
    dis_v[i]  = rsqrtf((float)(cv + 1));
    dis_cb[i] = rsqrtf((float)(cc + cv + 1));
  }
}

__global__ void fill_kernel(const int* __restrict__ eic, const int* __restrict__ eiv,
                            int* __restrict__ cur_c, int* __restrict__ col_c,
                            int* __restrict__ cur_v, int* __restrict__ col_v, int E) {
  int i = blockIdx.x * blockDim.x + threadIdx.x;
  if (i < E) {
    int s = eic[i], d = eic[E + i];
    int p = atomicAdd(&cur_c[d], 1);
    col_c[p] = s;
    s = eiv[i]; d = eiv[E + i];
    p = atomicAdd(&cur_v[d], 1);
    col_v[p] = s;
  }
}

// -------------------- fp32 GEMM: out[r][cc0..cc0+63] = scale[r] * sum_seg A_seg[r,:] @ W(rows seg*128.., cols wc0..) --------------------
// block: 256 thr = 32 rowgroups(2 rows) x 8 colgroups(8 cols); 64 rows/block.
// LDS: W chunk 64x64 (16KB) + X tile 64x68-pad (17KB) -> ~33.4KB -> 4 blocks/CU.
template <int NSEG>
__global__ __launch_bounds__(256) void gemm_n64(
    const float* __restrict__ A0, const float* __restrict__ A1,
    const float* __restrict__ W, int ldw, int wc0,
    const float* __restrict__ scale, float* __restrict__ C, int cc0, int M) {
  __shared__ float Wl[64 * 64];
  __shared__ float Xs[64 * 68];
  const int tid = threadIdx.x;
  const int cg = tid & 7, rg = tid >> 3;
  const int row0 = blockIdx.x * 64;
  float acc[2][8];
#pragma unroll
  for (int i = 0; i < 2; ++i)
#pragma unroll
    for (int j = 0; j < 8; ++j) acc[i][j] = 0.f;

#pragma unroll
  for (int seg = 0; seg < NSEG; ++seg) {
    const float* __restrict__ A = (seg == 0) ? A0 : A1;
#pragma unroll
    for (int kh = 0; kh < 2; ++kh) {
      const int kc = kh * 64;
      __syncthreads();
      for (int i = tid; i < 64 * 64; i += 256) {
        int k = i >> 6, c = i & 63;
        Wl[i] = W[(size_t)(seg * 128 + kc + k) * ldw + wc0 + c];
      }
      for (int i = tid; i < 64 * 16; i += 256) {
        int r = i >> 4, q = i & 15;
        float4 val = make_float4(0.f, 0.f, 0.f, 0.f);
        if (row0 + r < M)
          val = *(const float4*)(A + (size_t)(row0 + r) * 128 + kc + q * 4);
        *(float4*)(Xs + r * 68 + q * 4) = val;
      }
      __syncthreads();
      const float* xr0 = Xs + (rg * 2) * 68;
      const float* xr1 = xr0 + 68;
#pragma unroll 8
      for (int k = 0; k < 64; ++k) {
        float x0 = xr0[k], x1 = xr1[k];
        float4 wa = *(const float4*)(Wl + k * 64 + cg * 8);
        float4 wb = *(const float4*)(Wl + k * 64 + cg * 8 + 4);
        acc[0][0] = fmaf(x0, wa.x, acc[0][0]);
        acc[0][1] = fmaf(x0, wa.y, acc[0][1]);
        acc[0][2] = fmaf(x0, wa.z, acc[0][2]);
        acc[0][3] = fmaf(x0, wa.w, acc[0][3]);
        acc[0][4] = fmaf(x0, wb.x, acc[0][4]);
        acc[0][5] = fmaf(x0, wb.y, acc[0][5]);
        acc[0][6] = fmaf(x0, wb.z, acc[0][6]);
        acc[0][7] = fmaf(x0, wb.w, acc[0][7]);
        acc[1][0] = fmaf(x1, wa.x, acc[1][0]);
        acc[1][1] = fmaf(x1, wa.y, acc[1][1]);
        acc[1][2] = fmaf(x1, wa.z, acc[1][2]);
        acc[1][3] = fmaf(x1, wa.w, acc[1][3]);
        acc[1][4] = fmaf(x1, wb.x, acc[1][4]);
        acc[1][5] = fmaf(x1, wb.y, acc[1][5]);
        acc[1][6] = fmaf(x1, wb.z, acc[1][6]);
        acc[1][7] = fmaf(x1, wb.w, acc[1][7]);
      }
    }
  }
  int r0 = row0 + rg * 2;
  if (r0 < M) {
    float s0 = scale[r0];
    float4 o0 = make_float4(acc[0][0] * s0, acc[0][1] * s0, acc[0][2] * s0, acc[0][3] * s0);
    float4 o1 = make_float4(acc[0][4] * s0, acc[0][5] * s0, acc[0][6] * s0, acc[0][7] * s0);
    *(float4*)(C + (size_t)r0 * 128 + cc0 + cg * 8) = o0;
    *(float4*)(C + (size_t)r0 * 128 + cc0 + cg * 8 + 4) = o1;
  }
  if (r0 + 1 < M) {
    float s1 = scale[r0 + 1];
    float4 o0 = make_float4(acc[1][0] * s1, acc[1][1] * s1, acc[1][2] * s1, acc[1][3] * s1);
    float4 o1 = make_float4(acc[1][4] * s1, acc[1][5] * s1, acc[1][6] * s1, acc[1][7] * s1);
    *(float4*)(C + (size_t)(r0 + 1) * 128 + cc0 + cg * 8) = o0;
    *(float4*)(C + (size_t)(r0 + 1) * 128 + cc0 + cg * 8 + 4) = o1;
  }
}

// -------------------- fused gather + bias + LN + ELU for conv1|conv2 --------------------
// one wave per node; lane = feature col (0..63 of each half)
__global__ __launch_bounds__(256) void gather_ln12(
    const float* __restrict__ h12s,
    const int* __restrict__ row_c, const int* __restrict__ cnt_c, const int* __restrict__ col_c,
    const int* __restrict__ row_v, const int* __restrict__ cnt_v, const int* __restrict__ col_v,
    const float* __restrict__ dis_c, const float* __restrict__ dis_v,
    const float* __restrict__ b_corr, const float* __restrict__ g1, const float* __restrict__ bl1,
    const float* __restrict__ b_vendor, const float* __restrict__ g2, const float* __restrict__ bl2,
    float* __restrict__ h, int n) {
  const int lane = threadIdx.x & 63;
  const int v = blockIdx.x * 4 + (threadIdx.x >> 6);
  if (v >= n) return;
  const size_t vb = (size_t)v * 128;
  float acc1 = h12s[vb + lane];        // self loop (already dis-scaled)
  float acc2 = h12s[vb + 64 + lane];
  {
    int s = row_c[v], c = cnt_c[v], j = 0;
    for (; j + 4 <= c; j += 4) {
      int u0 = col_c[s + j], u1 = col_c[s + j + 1], u2 = col_c[s + j + 2], u3 = col_c[s + j + 3];
      float t0 = h12s[(size_t)u0 * 128 + lane];
      float t1 = h12s[(size_t)u1 * 128 + lane];
      float t2 = h12s[(size_t)u2 * 128 + lane];
      float t3 = h12s[(size_t)u3 * 128 + lane];
      acc1 += (t0 + t1) + (t2 + t3);
    }
    for (; j < c; ++j) acc1 += h12s[(size_t)col_c[s + j] * 128 + lane];
  }
  {
    int s = row_v[v], c = cnt_v[v], j = 0;
    for (; j + 4 <= c; j += 4) {
      int u0 = col_v[s + j], u1 = col_v[s + j + 1], u2 = col_v[s + j + 2], u3 = col_v[s + j + 3];
      float t0 = h12s[(size_t)u0 * 128 + 64 + lane];
      float t1 = h12s[(size_t)u1 * 128 + 64 + lane];
      float t2 = h12s[(size_t)u2 * 128 + 64 + lane];
      float t3 = h12s[(size_t)u3 * 128 + 64 + lane];
      acc2 += (t0 + t1) + (t2 + t3);
    }
    for (; j < c; ++j) acc2 += h12s[(size_t)col_v[s + j] * 128 + 64 + lane];
  }
  float o1 = dis_c[v] * acc1 + b_corr[lane];
  float o2 = dis_v[v] * acc2 + b_vendor[lane];
  float m1 = wave_sum(o1) * (1.f / 64.f);
  float m2 = wave_sum(o2) * (1.f / 64.f);
  float d1 = o1 - m1, d2 = o2 - m2;
  float var1 = wave_sum(d1 * d1) * (1.f / 64.f);
  float var2 = wave_sum(d2 * d2) * (1.f / 64.f);
  float n1 = d1 * rsqrtf(var1 + 1e-5f) * g1[lane] + bl1[lane];
  float n2 = d2 * rsqrtf(var2 + 1e-5f) * g2[lane] + bl2[lane];
  h[vb + lane] = (n1 > 0.f) ? n1 : expm1f(n1);
  h[vb + 64 + lane] = (n2 > 0.f) ? n2 : expm1f(n2);
}

// -------------------- fused gather(combined) + bias + LN + ELU + out-projection --------------------
__global__ __launch_bounds__(256) void gather_ln3_out(
    const float* __restrict__ h3s,
    const int* __restrict__ row_c, const int* __restrict__ cnt_c, const int* __restrict__ col_c,
    const int* __restrict__ row_v, const int* __restrict__ cnt_v, const int* __restrict__ col_v,
    const float* __restrict__ dis_cb,
    const float* __restrict__ b_ref, const float* __restrict__ g3, const float* __restrict__ bl3,
    const float* __restrict__ W_out, const float* __restrict__ b_out,
    float* __restrict__ out, int n) {
  const int lane = threadIdx.x & 63;
  const int v = blockIdx.x * 4 + (threadIdx.x >> 6);
  if (v >= n) return;
  const size_t vb = (size_t)v * 128;
  float a0 = h3s[vb + lane];           // self loop
  float a1 = h3s[vb + 64 + lane];
  {
    int s = row_c[v], c = cnt_c[v], j = 0;
    for (; j + 2 <= c; j += 2) {
      size_t b0 = (size_t)col_c[s + j] * 128, b1 = (size_t)col_c[s + j + 1] * 128;
      a0 += h3s[b0 + lane] + h3s[b1 + lane];
      a1 += h3s[b0 + 64 + lane] + h3s[b1 + 64 + lane];
    }
    for (; j < c; ++j) {
      size_t b = (size_t)col_c[s + j] * 128;
      a0 += h3s[b + lane];
      a1 += h3s[b + 64 + lane];
    }
  }
  {
    int s = row_v[v], c = cnt_v[v], j = 0;
    for (; j + 2 <= c; j += 2) {
      size_t b0 = (size_t)col_v[s + j] * 128, b1 = (size_t)col_v[s + j + 1] * 128;
      a0 += h3s[b0 + lane] + h3s[b1 + lane];
      a1 += h3s[b0 + 64 + lane] + h3s[b1 + 64 + lane];
    }
    for (; j < c; ++j) {
      size_t b = (size_t)col_v[s + j] * 128;
      a0 += h3s[b + lane];
      a1 += h3s[b + 64 + lane];
    }
  }
  float sc = dis_cb[v];
  float o0 = sc * a0 + b_ref[lane];
  float o1 = sc * a1 + b_ref[64 + lane];
  float m = wave_sum(o0 + o1) * (1.f / 128.f);
  float d0 = o0 - m, d1 = o1 - m;
  float var = wave_sum(d0 * d0 + d1 * d1) * (1.f / 128.f);
  float rs = rsqrtf(var + 1e-5f);
  float n0 = d0 * rs * g3[lane] + bl3[lane];
  float n1 = d1 * rs * g3[64 + lane] + bl3[64 + lane];
  float e0 = (n0 > 0.f) ? n0 : expm1f(n0);
  float e1 = (n1 > 0.f) ? n1 : expm1f(n1);
  float dot = wave_sum(e0 * W_out[lane] + e1 * W_out[64 + lane]);
  if (lane == 0) out[v] = dot + b_out[0];
}

// -------------------- launch --------------------
extern "C" void kernel_launch(void* const* d_in, const int* in_sizes, int n_in,
                              void* d_out, int out_size, void* d_ws, size_t ws_size,
                              hipStream_t stream) {
  const float* x        = (const float*)d_in[0];
  const int* eic        = (const int*)d_in[1];
  const int* eiv        = (const int*)d_in[2];
  const float* xl       = (const float*)d_in[3];
  const float* W_corr   = (const float*)d_in[4];
  const float* b_corr   = (const float*)d_in[5];
  const float* g_ln_c   = (const float*)d_in[6];
  const float* b_ln_c   = (const float*)d_in[7];
  const float* W_vendor = (const float*)d_in[8];
  const float* b_vendor = (const float*)d_in[9];
  const float* g_ln_v   = (const float*)d_in[10];
  const float* b_ln_v   = (const float*)d_in[11];
  const float* W_refine = (const float*)d_in[12];
  const float* b_refine = (const float*)d_in[13];
  const float* g_ln_r   = (const float*)d_in[14];
  const float* b_ln_r   = (const float*)d_in[15];
  const float* W_out    = (const float*)d_in[16];
  const float* b_out    = (const float*)d_in[17];
  float* out = (float*)d_out;

  const int N = in_sizes[0] / 128;
  const int E = in_sizes[1] / 2;

  int* iw = (int*)d_ws;
  int* cnt_c = iw;
  int* cnt_v = iw + N;
  int* row_c = iw + 2 * (size_t)N;
  int* row_v = iw + 3 * (size_t)N;
  int* cur_c = iw + 4 * (size_t)N;
  int* cur_v = iw + 5 * (size_t)N;
  int* col_c = iw + 6 * (size_t)N;
  int* col_v = iw + 6 * (size_t)N + E;
  float* fw = (float*)d_ws;
  float* dis_c  = fw + 6 * (size_t)N + 2 * (size_t)E;
  float* dis_v  = dis_c + N;
  float* dis_cb = dis_v + N;
  float* h12s = dis_cb + N;                 // N*128 floats (reused as h3s)
  float* h    = h12s + (size_t)N * 128;     // N*128 floats

  hipMemsetAsync(d_ws, 0, (size_t)2 * N * sizeof(int), stream);

  int eb = (E + 255) / 256;
  count_kernel<<<eb, 256, 0, stream>>>(eic, eiv, cnt_c, cnt_v, E);
  scan_kernel<<<2, 1024, 0, stream>>>(cnt_c, row_c, cur_c, cnt_v, row_v, cur_v, N);
  dis_kernel<<<(N + 255) / 256, 256, 0, stream>>>(cnt_c, cnt_v, dis_c, dis_v, dis_cb, N);
  fill_kernel<<<eb, 256, 0, stream>>>(eic, eiv, cur_c, col_c, cur_v, col_v, E);

  int gb = (N + 63) / 64;
  gemm_n64<1><<<gb, 256, 0, stream>>>(x, nullptr, W_corr, 64, 0, dis_c, h12s, 0, N);
  gemm_n64<2><<<gb, 256, 0, stream>>>(x, xl, W_vendor, 64, 0, dis_v, h12s, 64, N);

  int nb4 = (N + 3) / 4;
  gather_ln12<<<nb4, 256, 0, stream>>>(h12s, row_c, cnt_c, col_c, row_v, cnt_v, col_v,
                                       dis_c, dis_v, b_corr, g_ln_c, b_ln_c,
                                       b_vendor, g_ln_v, b_ln_v, h, N);

  float* h3s = h12s;  // h12s dead after gather_ln12
  gemm_n64<1><<<gb, 256, 0, stream>>>(h, nullptr, W_refine, 128, 0, dis_cb, h3s, 0, N);
  gemm_n64<1><<<gb, 256, 0, stream>>>(h, nullptr, W_refine, 128, 64, dis_cb, h3s, 64, N);

  gather_ln3_out<<<nb4, 256, 0, stream>>>(h3s, row_c, cnt_c, col_c, row_v, cnt_v, col_v,
                                          dis_cb, b_refine, g_ln_r, b_ln_r,
                                          W_out, b_out, out, N);
}

// Round 6
// 552.426 us; speedup vs baseline: 1.1999x; 1.1999x over previous
//
#include <hip/hip_runtime.h>
#include <math.h>

// -------------------- wave helpers --------------------
__device__ __forceinline__ float wave_sum(float x) {
#pragma unroll
  for (int off = 32; off > 0; off >>= 1) x += __shfl_xor(x, off, 64);
  return x;
}

// -------------------- edge prep --------------------
// count + rank: rank[i] = position of edge i within its dst bucket.
// 1.6M device-scope atomics total (the only atomic pass).
__global__ void count_kernel(const int* __restrict__ eic, const int* __restrict__ eiv,
                             int* __restrict__ cnt_c, int* __restrict__ cnt_v,
                             int* __restrict__ rank_c, int* __restrict__ rank_v, int E) {
  int i = blockIdx.x * blockDim.x + threadIdx.x;
  if (i < E) {
    rank_c[i] = atomicAdd(&cnt_c[eic[E + i]], 1);
    rank_v[i] = atomicAdd(&cnt_v[eiv[E + i]], 1);
  }
}

// one block per relation (grid=2, block=1024): exclusive scan of counts
__global__ void scan_kernel(const int* __restrict__ cnt_c, int* __restrict__ row_c,
                            const int* __restrict__ cnt_v, int* __restrict__ row_v,
                            int n) {
  const int* cnt = blockIdx.x ? cnt_v : cnt_c;
  int* row = blockIdx.x ? row_v : row_c;
  __shared__ int wsum[16];
  __shared__ int stot;
  const int tid = threadIdx.x;
  const int lane = tid & 63, wid = tid >> 6;
  int carry = 0;
  for (int base = 0; base < n; base += 1024) {
    int i = base + tid;
    int v = (i < n) ? cnt[i] : 0;
    int x = v;
#pragma unroll
    for (int off = 1; off < 64; off <<= 1) {
      int y = __shfl_up(x, off, 64);
      if (lane >= off) x += y;
    }
    if (lane == 63) wsum[wid] = x;
    __syncthreads();
    if (tid == 0) {
      int s = 0;
#pragma unroll
      for (int w = 0; w < 16; ++w) { int t = wsum[w]; wsum[w] = s; s += t; }
      stot = s;
    }
    __syncthreads();
    int excl = carry + wsum[wid] + (x - v);
    if (i < n) row[i] = excl;
    carry += stot;
    __syncthreads();
  }
}

__global__ void dis_kernel(const int* __restrict__ cnt_c, const int* __restrict__ cnt_v,
                           float* __restrict__ dis_c, float* __restrict__ dis_v,
                           float* __restrict__ dis_cb, int n) {
  int i = blockIdx.x * blockDim.x + threadIdx.x;
  if (i < n) {
    int cc = cnt_c[i], cv = cnt_v[i];
    dis_c[i]  = rsqrtf((float)(cc + 1));
    dis_v[i]  = rsqrtf((float)(cv + 1));
    dis_cb[i] = rsqrtf((float)(cc + cv + 1));
  }
}

// atomic-free fill: position = row[dst] + rank[i]. Plain 4B scattered writes
// into L2-resident col arrays (6.4MB payload, no coherence-point RMW).
__global__ void fill_kernel(const int* __restrict__ eic, const int* __restrict__ eiv,
                            const int* __restrict__ rank_c, const int* __restrict__ rank_v,
                            const int* __restrict__ row_c, const int* __restrict__ row_v,
                            int* __restrict__ col_c, int* __restrict__ col_v, int E) {
  int i = blockIdx.x * blockDim.x + threadIdx.x;
  if (i < E) {
    int d = eic[E + i];
    col_c[row_c[d] + rank_c[i]] = eic[i];
    d = eiv[E + i];
    col_v[row_v[d] + rank_v[i]] = eiv[i];
  }
}

// -------------------- fp32 GEMM: out[r][cc0..cc0+63] = scale[r] * sum_seg A_seg[r,:] @ W(rows seg*128.., cols wc0..) --------------------
template <int NSEG>
__global__ __launch_bounds__(256) void gemm_n64(
    const float* __restrict__ A0, const float* __restrict__ A1,
    const float* __restrict__ W, int ldw, int wc0,
    const float* __restrict__ scale, float* __restrict__ C, int cc0, int M) {
  __shared__ float Wl[64 * 64];
  __shared__ float Xs[64 * 68];
  const int tid = threadIdx.x;
  const int cg = tid & 7, rg = tid >> 3;
  const int row0 = blockIdx.x * 64;
  float acc[2][8];
#pragma unroll
  for (int i = 0; i < 2; ++i)
#pragma unroll
    for (int j = 0; j < 8; ++j) acc[i][j] = 0.f;

#pragma unroll
  for (int seg = 0; seg < NSEG; ++seg) {
    const float* __restrict__ A = (seg == 0) ? A0 : A1;
#pragma unroll
    for (int kh = 0; kh < 2; ++kh) {
      const int kc = kh * 64;
      __syncthreads();
      for (int i = tid; i < 64 * 64; i += 256) {
        int k = i >> 6, c = i & 63;
        Wl[i] = W[(size_t)(seg * 128 + kc + k) * ldw + wc0 + c];
      }
      for (int i = tid; i < 64 * 16; i += 256) {
        int r = i >> 4, q = i & 15;
        float4 val = make_float4(0.f, 0.f, 0.f, 0.f);
        if (row0 + r < M)
          val = *(const float4*)(A + (size_t)(row0 + r) * 128 + kc + q * 4);
        *(float4*)(Xs + r * 68 + q * 4) = val;
      }
      __syncthreads();
      const float* xr0 = Xs + (rg * 2) * 68;
      const float* xr1 = xr0 + 68;
#pragma unroll 8
      for (int k = 0; k < 64; ++k) {
        float x0 = xr0[k], x1 = xr1[k];
        float4 wa = *(const float4*)(Wl + k * 64 + cg * 8);
        float4 wb = *(const float4*)(Wl + k * 64 + cg * 8 + 4);
        acc[0][0] = fmaf(x0, wa.x, acc[0][0]);
        acc[0][1] = fmaf(x0, wa.y, acc[0][1]);
        acc[0][2] = fmaf(x0, wa.z, acc[0][2]);
        acc[0][3] = fmaf(x0, wa.w, acc[0][3]);
        acc[0][4] = fmaf(x0, wb.x, acc[0][4]);
        acc[0][5] = fmaf(x0, wb.y, acc[0][5]);
        acc[0][6] = fmaf(x0, wb.z, acc[0][6]);
        acc[0][7] = fmaf(x0, wb.w, acc[0][7]);
        acc[1][0] = fmaf(x1, wa.x, acc[1][0]);
        acc[1][1] = fmaf(x1, wa.y, acc[1][1]);
        acc[1][2] = fmaf(x1, wa.z, acc[1][2]);
        acc[1][3] = fmaf(x1, wa.w, acc[1][3]);
        acc[1][4] = fmaf(x1, wb.x, acc[1][4]);
        acc[1][5] = fmaf(x1, wb.y, acc[1][5]);
        acc[1][6] = fmaf(x1, wb.z, acc[1][6]);
        acc[1][7] = fmaf(x1, wb.w, acc[1][7]);
      }
    }
  }
  int r0 = row0 + rg * 2;
  if (r0 < M) {
    float s0 = scale[r0];
    float4 o0 = make_float4(acc[0][0] * s0, acc[0][1] * s0, acc[0][2] * s0, acc[0][3] * s0);
    float4 o1 = make_float4(acc[0][4] * s0, acc[0][5] * s0, acc[0][6] * s0, acc[0][7] * s0);
    *(float4*)(C + (size_t)r0 * 128 + cc0 + cg * 8) = o0;
    *(float4*)(C + (size_t)r0 * 128 + cc0 + cg * 8 + 4) = o1;
  }
  if (r0 + 1 < M) {
    float s1 = scale[r0 + 1];
    float4 o0 = make_float4(acc[1][0] * s1, acc[1][1] * s1, acc[1][2] * s1, acc[1][3] * s1);
    float4 o1 = make_float4(acc[1][4] * s1, acc[1][5] * s1, acc[1][6] * s1, acc[1][7] * s1);
    *(float4*)(C + (size_t)(r0 + 1) * 128 + cc0 + cg * 8) = o0;
    *(float4*)(C + (size_t)(r0 + 1) * 128 + cc0 + cg * 8 + 4) = o1;
  }
}

// -------------------- fused gather + bias + LN + ELU for conv1|conv2 --------------------
// wave per node; 4 quarter-waves: each qw's 16 lanes read one neighbor's 256B
// half-row as float4 (4 neighbors in flight per issue, 8 with unroll-2).
__global__ __launch_bounds__(256) void gather_ln12(
    const float* __restrict__ h12s,
    const int* __restrict__ row_c, const int* __restrict__ cnt_c, const int* __restrict__ col_c,
    const int* __restrict__ row_v, const int* __restrict__ cnt_v, const int* __restrict__ col_v,
    const float* __restrict__ dis_c, const float* __restrict__ dis_v,
    const float* __restrict__ b_corr, const float* __restrict__ g1, const float* __restrict__ bl1,
    const float* __restrict__ b_vendor, const float* __restrict__ g2, const float* __restrict__ bl2,
    float* __restrict__ h, int n) {
  const int lane = threadIdx.x & 63;
  const int v = blockIdx.x * 4 + (threadIdx.x >> 6);
  if (v >= n) return;
  const int qw = lane >> 4;   // 0..3
  const int sl = lane & 15;   // feature block: features sl*4 .. sl*4+3
  const size_t vb = (size_t)v * 128;
  float ac[4] = {0.f, 0.f, 0.f, 0.f};
  float av[4] = {0.f, 0.f, 0.f, 0.f};
  if (qw == 0) {  // self loop counted once
    float4 s4 = *(const float4*)(h12s + vb + sl * 4);
    float4 t4 = *(const float4*)(h12s + vb + 64 + sl * 4);
    ac[0] = s4.x; ac[1] = s4.y; ac[2] = s4.z; ac[3] = s4.w;
    av[0] = t4.x; av[1] = t4.y; av[2] = t4.z; av[3] = t4.w;
  }
  {
    int s = row_c[v], c = cnt_c[v], j = 0;
    for (; j + 8 <= c; j += 8) {
      int u0 = col_c[s + j + qw], u1 = col_c[s + j + 4 + qw];
      float4 t0 = *(const float4*)(h12s + (size_t)u0 * 128 + sl * 4);
      float4 t1 = *(const float4*)(h12s + (size_t)u1 * 128 + sl * 4);
      ac[0] += t0.x + t1.x; ac[1] += t0.y + t1.y; ac[2] += t0.z + t1.z; ac[3] += t0.w + t1.w;
    }
    for (; j < c; j += 4) {
      if (j + qw < c) {
        int u = col_c[s + j + qw];
        float4 t = *(const float4*)(h12s + (size_t)u * 128 + sl * 4);
        ac[0] += t.x; ac[1] += t.y; ac[2] += t.z; ac[3] += t.w;
      }
    }
  }
  {
    int s = row_v[v], c = cnt_v[v], j = 0;
    for (; j + 8 <= c; j += 8) {
      int u0 = col_v[s + j + qw], u1 = col_v[s + j + 4 + qw];
      float4 t0 = *(const float4*)(h12s + (size_t)u0 * 128 + 64 + sl * 4);
      float4 t1 = *(const float4*)(h12s + (size_t)u1 * 128 + 64 + sl * 4);
      av[0] += t0.x + t1.x; av[1] += t0.y + t1.y; av[2] += t0.z + t1.z; av[3] += t0.w + t1.w;
    }
    for (; j < c; j += 4) {
      if (j + qw < c) {
        int u = col_v[s + j + qw];
        float4 t = *(const float4*)(h12s + (size_t)u * 128 + 64 + sl * 4);
        av[0] += t.x; av[1] += t.y; av[2] += t.z; av[3] += t.w;
      }
    }
  }
#pragma unroll
  for (int k = 0; k < 4; ++k) {
    ac[k] += __shfl_xor(ac[k], 16, 64); ac[k] += __shfl_xor(ac[k], 32, 64);
    av[k] += __shfl_xor(av[k], 16, 64); av[k] += __shfl_xor(av[k], 32, 64);
  }
  const float dc = dis_c[v], dv = dis_v[v];
  float4 bc4 = *(const float4*)(b_corr + sl * 4);
  float4 bv4 = *(const float4*)(b_vendor + sl * 4);
  float oc[4], ov[4];
  oc[0] = dc * ac[0] + bc4.x; oc[1] = dc * ac[1] + bc4.y;
  oc[2] = dc * ac[2] + bc4.z; oc[3] = dc * ac[3] + bc4.w;
  ov[0] = dv * av[0] + bv4.x; ov[1] = dv * av[1] + bv4.y;
  ov[2] = dv * av[2] + bv4.z; ov[3] = dv * av[3] + bv4.w;
  // each feature appears in 4 lanes -> divide wave_sum by 4*64
  float m1 = wave_sum(oc[0] + oc[1] + oc[2] + oc[3]) * (1.f / 256.f);
  float m2 = wave_sum(ov[0] + ov[1] + ov[2] + ov[3]) * (1.f / 256.f);
  float dcv[4], dvv[4], q1 = 0.f, q2 = 0.f;
#pragma unroll
  for (int k = 0; k < 4; ++k) {
    dcv[k] = oc[k] - m1; q1 += dcv[k] * dcv[k];
    dvv[k] = ov[k] - m2; q2 += dvv[k] * dvv[k];
  }
  float rs1 = rsqrtf(wave_sum(q1) * (1.f / 256.f) + 1e-5f);
  float rs2 = rsqrtf(wave_sum(q2) * (1.f / 256.f) + 1e-5f);
  float4 g14 = *(const float4*)(g1 + sl * 4);
  float4 l14 = *(const float4*)(bl1 + sl * 4);
  float4 g24 = *(const float4*)(g2 + sl * 4);
  float4 l24 = *(const float4*)(bl2 + sl * 4);
  float nc[4], nv[4];
  nc[0] = dcv[0] * rs1 * g14.x + l14.x; nc[1] = dcv[1] * rs1 * g14.y + l14.y;
  nc[2] = dcv[2] * rs1 * g14.z + l14.z; nc[3] = dcv[3] * rs1 * g14.w + l14.w;
  nv[0] = dvv[0] * rs2 * g24.x + l24.x; nv[1] = dvv[1] * rs2 * g24.y + l24.y;
  nv[2] = dvv[2] * rs2 * g24.z + l24.z; nv[3] = dvv[3] * rs2 * g24.w + l24.w;
#pragma unroll
  for (int k = 0; k < 4; ++k) {
    nc[k] = (nc[k] > 0.f) ? nc[k] : expm1f(nc[k]);
    nv[k] = (nv[k] > 0.f) ? nv[k] : expm1f(nv[k]);
  }
  if (qw == 0) {
    *(float4*)(h + vb + sl * 4) = make_float4(nc[0], nc[1], nc[2], nc[3]);
  } else if (qw == 1) {
    *(float4*)(h + vb + 64 + sl * 4) = make_float4(nv[0], nv[1], nv[2], nv[3]);
  }
}

// -------------------- fused gather(combined) + bias + LN + ELU + out-projection --------------------
// wave per node; 2 half-waves: each hw's 32 lanes read one neighbor's 512B row
// as float4 (2 neighbors per issue, 4 in flight with unroll-2).
__global__ __launch_bounds__(256) void gather_ln3_out(
    const float* __restrict__ h3s,
    const int* __restrict__ row_c, const int* __restrict__ cnt_c, const int* __restrict__ col_c,
    const int* __restrict__ row_v, const int* __restrict__ cnt_v, const int* __restrict__ col_v,
    const float* __restrict__ dis_cb,
    const float* __restrict__ b_ref, const float* __restrict__ g3, const float* __restrict__ bl3,
    const float* __restrict__ W_out, const float* __restrict__ b_out,
    float* __restrict__ out, int n) {
  const int lane = threadIdx.x & 63;
  const int v = blockIdx.x * 4 + (threadIdx.x >> 6);
  if (v >= n) return;
  const int hw = lane >> 5;   // 0..1
  const int sl = lane & 31;   // feature block: features sl*4 .. sl*4+3
  const size_t vb = (size_t)v * 128;
  float a[4] = {0.f, 0.f, 0.f, 0.f};
  if (hw == 0) {  // self loop counted once
    float4 s4 = *(const float4*)(h3s + vb + sl * 4);
    a[0] = s4.x; a[1] = s4.y; a[2] = s4.z; a[3] = s4.w;
  }
  {
    int s = row_c[v], c = cnt_c[v], j = 0;
    for (; j + 4 <= c; j += 4) {
      int u0 = col_c[s + j + hw], u1 = col_c[s + j + 2 + hw];
      float4 t0 = *(const float4*)(h3s + (size_t)u0 * 128 + sl * 4);
      float4 t1 = *(const float4*)(h3s + (size_t)u1 * 128 + sl * 4);
      a[0] += t0.x + t1.x; a[1] += t0.y + t1.y; a[2] += t0.z + t1.z; a[3] += t0.w + t1.w;
    }
    for (; j < c; j += 2) {
      if (j + hw < c) {
        int u = col_c[s + j + hw];
        float4 t = *(const float4*)(h3s + (size_t)u * 128 + sl * 4);
        a[0] += t.x; a[1] += t.y; a[2] += t.z; a[3] += t.w;
      }
    }
  }
  {
    int s = row_v[v], c = cnt_v[v], j = 0;
    for (; j + 4 <= c; j += 4) {
      int u0 = col_v[s + j + hw], u1 = col_v[s + j + 2 + hw];
      float4 t0 = *(const float4*)(h3s + (size_t)u0 * 128 + sl * 4);
      float4 t1 = *(const float4*)(h3s + (size_t)u1 * 128 + sl * 4);
      a[0] += t0.x + t1.x; a[1] += t0.y + t1.y; a[2] += t0.z + t1.z; a[3] += t0.w + t1.w;
    }
    for (; j < c; j += 2) {
      if (j + hw < c) {
        int u = col_v[s + j + hw];
        float4 t = *(const float4*)(h3s + (size_t)u * 128 + sl * 4);
        a[0] += t.x; a[1] += t.y; a[2] += t.z; a[3] += t.w;
      }
    }
  }
#pragma unroll
  for (int k = 0; k < 4; ++k) a[k] += __shfl_xor(a[k], 32, 64);
  const float sc = dis_cb[v];
  float4 br4 = *(const float4*)(b_ref + sl * 4);
  float o[4];
  o[0] = sc * a[0] + br4.x; o[1] = sc * a[1] + br4.y;
  o[2] = sc * a[2] + br4.z; o[3] = sc * a[3] + br4.w;
  // each feature appears in 2 lanes -> divide wave_sum by 2*128
  float m = wave_sum(o[0] + o[1] + o[2] + o[3]) * (1.f / 256.f);
  float d[4], q = 0.f;
#pragma unroll
  for (int k = 0; k < 4; ++k) { d[k] = o[k] - m; q += d[k] * d[k]; }
  float rs = rsqrtf(wave_sum(q) * (1.f / 256.f) + 1e-5f);
  float4 g34 = *(const float4*)(g3 + sl * 4);
  float4 l34 = *(const float4*)(bl3 + sl * 4);
  float4 w4  = *(const float4*)(W_out + sl * 4);
  float e0 = d[0] * rs * g34.x + l34.x;
  float e1 = d[1] * rs * g34.y + l34.y;
  float e2 = d[2] * rs * g34.z + l34.z;
  float e3 = d[3] * rs * g34.w + l34.w;
  e0 = (e0 > 0.f) ? e0 : expm1f(e0);
  e1 = (e1 > 0.f) ? e1 : expm1f(e1);
  e2 = (e2 > 0.f) ? e2 : expm1f(e2);
  e3 = (e3 > 0.f) ? e3 : expm1f(e3);
  float dot = wave_sum(e0 * w4.x + e1 * w4.y + e2 * w4.z + e3 * w4.w) * 0.5f;
  if (lane == 0) out[v] = dot + b_out[0];
}

// -------------------- launch --------------------
extern "C" void kernel_launch(void* const* d_in, const int* in_sizes, int n_in,
                              void* d_out, int out_size, void* d_ws, size_t ws_size,
                              hipStream_t stream) {
  const float* x        = (const float*)d_in[0];
  const int* eic        = (const int*)d_in[1];
  const int* eiv        = (const int*)d_in[2];
  const float* xl       = (const float*)d_in[3];
  const float* W_corr   = (const float*)d_in[4];
  const float* b_corr   = (const float*)d_in[5];
  const float* g_ln_c   = (const float*)d_in[6];
  const float* b_ln_c   = (const float*)d_in[7];
  const float* W_vendor = (const float*)d_in[8];
  const float* b_vendor = (const float*)d_in[9];
  const float* g_ln_v   = (const float*)d_in[10];
  const float* b_ln_v   = (const float*)d_in[11];
  const float* W_refine = (const float*)d_in[12];
  const float* b_refine = (const float*)d_in[13];
  const float* g_ln_r   = (const float*)d_in[14];
  const float* b_ln_r   = (const float*)d_in[15];
  const float* W_out    = (const float*)d_in[16];
  const float* b_out    = (const float*)d_in[17];
  float* out = (float*)d_out;

  const int N = in_sizes[0] / 128;
  const int E = in_sizes[1] / 2;

  // layout: [cnt_c N][cnt_v N][row_c N][row_v N][col_c E][col_v E]
  //         [dis_c N][dis_v N][dis_cb N][h12s 128N][h 128N]
  // rank_c/rank_v (2E ints) alias h12s (dead until the GEMMs run).
  int* iw = (int*)d_ws;
  int* cnt_c = iw;
  int* cnt_v = iw + N;
  int* row_c = iw + 2 * (size_t)N;
  int* row_v = iw + 3 * (size_t)N;
  int* col_c = iw + 4 * (size_t)N;
  int* col_v = iw + 4 * (size_t)N + E;
  float* fw = (float*)d_ws;
  float* dis_c  = fw + 4 * (size_t)N + 2 * (size_t)E;
  float* dis_v  = dis_c + N;
  float* dis_cb = dis_v + N;
  float* h12s = dis_cb + N;                 // N*128 floats (reused as h3s)
  float* h    = h12s + (size_t)N * 128;     // N*128 floats
  int* rank_c = (int*)h12s;                 // aliases h12s during prep
  int* rank_v = rank_c + E;

  hipMemsetAsync(d_ws, 0, (size_t)2 * N * sizeof(int), stream);

  int eb = (E + 255) / 256;
  count_kernel<<<eb, 256, 0, stream>>>(eic, eiv, cnt_c, cnt_v, rank_c, rank_v, E);
  scan_kernel<<<2, 1024, 0, stream>>>(cnt_c, row_c, cnt_v, row_v, N);
  dis_kernel<<<(N + 255) / 256, 256, 0, stream>>>(cnt_c, cnt_v, dis_c, dis_v, dis_cb, N);
  fill_kernel<<<eb, 256, 0, stream>>>(eic, eiv, rank_c, rank_v, row_c, row_v, col_c, col_v, E);

  int gb = (N + 63) / 64;
  gemm_n64<1><<<gb, 256, 0, stream>>>(x, nullptr, W_corr, 64, 0, dis_c, h12s, 0, N);
  gemm_n64<2><<<gb, 256, 0, stream>>>(x, xl, W_vendor, 64, 0, dis_v, h12s, 64, N);

  int nb4 = (N + 3) / 4;
  gather_ln12<<<nb4, 256, 0, stream>>>(h12s, row_c, cnt_c, col_c, row_v, cnt_v, col_v,
                                       dis_c, dis_v, b_corr, g_ln_c, b_ln_c,
                                       b_vendor, g_ln_v, b_ln_v, h, N);

  float* h3s = h12s;  // h12s dead after gather_ln12
  gemm_n64<1><<<gb, 256, 0, stream>>>(h, nullptr, W_refine, 128, 0, dis_cb, h3s, 0, N);
  gemm_n64<1><<<gb, 256, 0, stream>>>(h, nullptr, W_refine, 128, 64, dis_cb, h3s, 64, N);

  gather_ln3_out<<<nb4, 256, 0, stream>>>(h3s, row_c, cnt_c, col_c, row_v, cnt_v, col_v,
                                          dis_cb, b_refine, g_ln_r, b_ln_r,
                                          W_out, b_out, out, N);
}

// Round 12
// 519.406 us; speedup vs baseline: 1.2762x; 1.0636x over previous
//
#include <hip/hip_runtime.h>
#include <math.h>

// -------------------- helpers --------------------
__device__ __forceinline__ float wave_sum(float x) {
#pragma unroll
  for (int off = 32; off > 0; off >>= 1) x += __shfl_xor(x, off, 64);
  return x;
}

__device__ __forceinline__ unsigned short f2bf(float f) {  // RNE
  unsigned int u = __float_as_uint(f);
  return (unsigned short)((u + 0x7FFFu + ((u >> 16) & 1u)) >> 16);
}
__device__ __forceinline__ unsigned int pack2(float a, float b) {
  return (unsigned int)f2bf(a) | ((unsigned int)f2bf(b) << 16);
}
// unpack uint2 -> 4 floats (bf16 lo/hi per dword)
__device__ __forceinline__ void unpk4(uint2 p, float& f0, float& f1, float& f2, float& f3) {
  f0 = __uint_as_float(p.x << 16);
  f1 = __uint_as_float(p.x & 0xffff0000u);
  f2 = __uint_as_float(p.y << 16);
  f3 = __uint_as_float(p.y & 0xffff0000u);
}

// -------------------- edge prep --------------------
// count + rank: rank[i] = position of edge i within its dst bucket.
__global__ void count_kernel(const int* __restrict__ eic, const int* __restrict__ eiv,
                             int* __restrict__ cnt_c, int* __restrict__ cnt_v,
                             int* __restrict__ rank_c, int* __restrict__ rank_v, int E) {
  int i = blockIdx.x * blockDim.x + threadIdx.x;
  if (i < E) {
    rank_c[i] = atomicAdd(&cnt_c[eic[E + i]], 1);
    rank_v[i] = atomicAdd(&cnt_v[eiv[E + i]], 1);
  }
}

__global__ void scan_kernel(const int* __restrict__ cnt_c, int* __restrict__ row_c,
                            const int* __restrict__ cnt_v, int* __restrict__ row_v,
                            int n) {
  const int* cnt = blockIdx.x ? cnt_v : cnt_c;
  int* row = blockIdx.x ? row_v : row_c;
  __shared__ int wsum[16];
  __shared__ int stot;
  const int tid = threadIdx.x;
  const int lane = tid & 63, wid = tid >> 6;
  int carry = 0;
  for (int base = 0; base < n; base += 1024) {
    int i = base + tid;
    int v = (i < n) ? cnt[i] : 0;
    int x = v;
#pragma unroll
    for (int off = 1; off < 64; off <<= 1) {
      int y = __shfl_up(x, off, 64);
      if (lane >= off) x += y;
    }
    if (lane == 63) wsum[wid] = x;
    __syncthreads();
    if (tid == 0) {
      int s = 0;
#pragma unroll
      for (int w = 0; w < 16; ++w) { int t = wsum[w]; wsum[w] = s; s += t; }
      stot = s;
    }
    __syncthreads();
    int excl = carry + wsum[wid] + (x - v);
    if (i < n) row[i] = excl;
    carry += stot;
    __syncthreads();
  }
}

__global__ void dis_kernel(const int* __restrict__ cnt_c, const int* __restrict__ cnt_v,
                           float* __restrict__ dis_c, float* __restrict__ dis_v,
                           float* __restrict__ dis_cb, int n) {
  int i = blockIdx.x * blockDim.x + threadIdx.x;
  if (i < n) {
    int cc = cnt_c[i], cv = cnt_v[i];
    dis_c[i]  = rsqrtf((float)(cc + 1));
    dis_v[i]  = rsqrtf((float)(cv + 1));
    dis_cb[i] = rsqrtf((float)(cc + cv + 1));
  }
}

// atomic-free fill: position = row[dst] + rank[i].
__global__ void fill_kernel(const int* __restrict__ eic, const int* __restrict__ eiv,
                            const int* __restrict__ rank_c, const int* __restrict__ rank_v,
                            const int* __restrict__ row_c, const int* __restrict__ row_v,
                            int* __restrict__ col_c, int* __restrict__ col_v, int E) {
  int i = blockIdx.x * blockDim.x + threadIdx.x;
  if (i < E) {
    int d = eic[E + i];
    col_c[row_c[d] + rank_c[i]] = eic[i];
    d = eiv[E + i];
    col_v[row_v[d] + rank_v[i]] = eiv[i];
  }
}

// -------------------- fp32 GEMM -> bf16 output --------------------
// out[r][cc0..cc0+63] = bf16( scale[r] * sum_seg A_seg[r,:] @ W(...) )
template <int NSEG>
__global__ __launch_bounds__(256) void gemm_n64(
    const float* __restrict__ A0, const float* __restrict__ A1,
    const float* __restrict__ W, int ldw, int wc0,
    const float* __restrict__ scale, unsigned short* __restrict__ Cb, int cc0, int M) {
  __shared__ float Wl[64 * 64];
  __shared__ float Xs[64 * 68];
  const int tid = threadIdx.x;
  const int cg = tid & 7, rg = tid >> 3;
  const int row0 = blockIdx.x * 64;
  float acc[2][8];
#pragma unroll
  for (int i = 0; i < 2; ++i)
#pragma unroll
    for (int j = 0; j < 8; ++j) acc[i][j] = 0.f;

#pragma unroll
  for (int seg = 0; seg < NSEG; ++seg) {
    const float* __restrict__ A = (seg == 0) ? A0 : A1;
#pragma unroll
    for (int kh = 0; kh < 2; ++kh) {
      const int kc = kh * 64;
      __syncthreads();
      for (int i = tid; i < 64 * 64; i += 256) {
        int k = i >> 6, c = i & 63;
        Wl[i] = W[(size_t)(seg * 128 + kc + k) * ldw + wc0 + c];
      }
      for (int i = tid; i < 64 * 16; i += 256) {
        int r = i >> 4, q = i & 15;
        float4 val = make_float4(0.f, 0.f, 0.f, 0.f);
        if (row0 + r < M)
          val = *(const float4*)(A + (size_t)(row0 + r) * 128 + kc + q * 4);
        *(float4*)(Xs + r * 68 + q * 4) = val;
      }
      __syncthreads();
      const float* xr0 = Xs + (rg * 2) * 68;
      const float* xr1 = xr0 + 68;
#pragma unroll 8
      for (int k = 0; k < 64; ++k) {
        float x0 = xr0[k], x1 = xr1[k];
        float4 wa = *(const float4*)(Wl + k * 64 + cg * 8);
        float4 wb = *(const float4*)(Wl + k * 64 + cg * 8 + 4);
        acc[0][0] = fmaf(x0, wa.x, acc[0][0]);
        acc[0][1] = fmaf(x0, wa.y, acc[0][1]);
        acc[0][2] = fmaf(x0, wa.z, acc[0][2]);
        acc[0][3] = fmaf(x0, wa.w, acc[0][3]);
        acc[0][4] = fmaf(x0, wb.x, acc[0][4]);
        acc[0][5] = fmaf(x0, wb.y, acc[0][5]);
        acc[0][6] = fmaf(x0, wb.z, acc[0][6]);
        acc[0][7] = fmaf(x0, wb.w, acc[0][7]);
        acc[1][0] = fmaf(x1, wa.x, acc[1][0]);
        acc[1][1] = fmaf(x1, wa.y, acc[1][1]);
        acc[1][2] = fmaf(x1, wa.z, acc[1][2]);
        acc[1][3] = fmaf(x1, wa.w, acc[1][3]);
        acc[1][4] = fmaf(x1, wb.x, acc[1][4]);
        acc[1][5] = fmaf(x1, wb.y, acc[1][5]);
        acc[1][6] = fmaf(x1, wb.z, acc[1][6]);
        acc[1][7] = fmaf(x1, wb.w, acc[1][7]);
      }
    }
  }
  int r0 = row0 + rg * 2;
  if (r0 < M) {
    float s = scale[r0];
    uint4 o;
    o.x = pack2(acc[0][0] * s, acc[0][1] * s);
    o.y = pack2(acc[0][2] * s, acc[0][3] * s);
    o.z = pack2(acc[0][4] * s, acc[0][5] * s);
    o.w = pack2(acc[0][6] * s, acc[0][7] * s);
    *(uint4*)(Cb + (size_t)r0 * 128 + cc0 + cg * 8) = o;
  }
  if (r0 + 1 < M) {
    float s = scale[r0 + 1];
    uint4 o;
    o.x = pack2(acc[1][0] * s, acc[1][1] * s);
    o.y = pack2(acc[1][2] * s, acc[1][3] * s);
    o.z = pack2(acc[1][4] * s, acc[1][5] * s);
    o.w = pack2(acc[1][6] * s, acc[1][7] * s);
    *(uint4*)(Cb + (size_t)(r0 + 1) * 128 + cc0 + cg * 8) = o;
  }
}

// -------------------- fused gather + bias + LN + ELU for conv1|conv2 --------------------
// wave per node; 4 quarter-waves: each qw's 16 lanes read one neighbor's 128B
// bf16 half-row as uint2 (4 neighbors per issue, 8 in flight with unroll-2).
__global__ __launch_bounds__(256) void gather_ln12(
    const unsigned short* __restrict__ h12s,
    const int* __restrict__ row_c, const int* __restrict__ cnt_c, const int* __restrict__ col_c,
    const int* __restrict__ row_v, const int* __restrict__ cnt_v, const int* __restrict__ col_v,
    const float* __restrict__ dis_c, const float* __restrict__ dis_v,
    const float* __restrict__ b_corr, const float* __restrict__ g1, const float* __restrict__ bl1,
    const float* __restrict__ b_vendor, const float* __restrict__ g2, const float* __restrict__ bl2,
    float* __restrict__ h, int n) {
  const int lane = threadIdx.x & 63;
  const int v = blockIdx.x * 4 + (threadIdx.x >> 6);
  if (v >= n) return;
  const int qw = lane >> 4;   // 0..3
  const int sl = lane & 15;   // features 4sl..4sl+3 of the 64-col half
  const size_t vb = (size_t)v * 128;
  float ac[4] = {0.f, 0.f, 0.f, 0.f};
  float av[4] = {0.f, 0.f, 0.f, 0.f};
  if (qw == 0) {  // self loop counted once
    float s0, s1, s2, s3;
    unpk4(*((const uint2*)(h12s + vb) + sl), s0, s1, s2, s3);
    ac[0] = s0; ac[1] = s1; ac[2] = s2; ac[3] = s3;
    unpk4(*((const uint2*)(h12s + vb + 64) + sl), s0, s1, s2, s3);
    av[0] = s0; av[1] = s1; av[2] = s2; av[3] = s3;
  }
  {
    int s = row_c[v], c = cnt_c[v], j = 0;
    for (; j + 8 <= c; j += 8) {
      int u0 = col_c[s + j + qw], u1 = col_c[s + j + 4 + qw];
      uint2 p0 = *((const uint2*)(h12s + (size_t)u0 * 128) + sl);
      uint2 p1 = *((const uint2*)(h12s + (size_t)u1 * 128) + sl);
      float a0, a1, a2, a3, b0, b1, b2, b3;
      unpk4(p0, a0, a1, a2, a3); unpk4(p1, b0, b1, b2, b3);
      ac[0] += a0 + b0; ac[1] += a1 + b1; ac[2] += a2 + b2; ac[3] += a3 + b3;
    }
    for (; j < c; j += 4) {
      if (j + qw < c) {
        int u = col_c[s + j + qw];
        float a0, a1, a2, a3;
        unpk4(*((const uint2*)(h12s + (size_t)u * 128) + sl), a0, a1, a2, a3);
        ac[0] += a0; ac[1] += a1; ac[2] += a2; ac[3] += a3;
      }
    }
  }
  {
    int s = row_v[v], c = cnt_v[v], j = 0;
    for (; j + 8 <= c; j += 8) {
      int u0 = col_v[s + j + qw], u1 = col_v[s + j + 4 + qw];
      uint2 p0 = *((const uint2*)(h12s + (size_t)u0 * 128 + 64) + sl);
      uint2 p1 = *((const uint2*)(h12s + (size_t)u1 * 128 + 64) + sl);
      float a0, a1, a2, a3, b0, b1, b2, b3;
      unpk4(p0, a0, a1, a2, a3); unpk4(p1, b0, b1, b2, b3);
      av[0] += a0 + b0; av[1] += a1 + b1; av[2] += a2 + b2; av[3] += a3 + b3;
    }
    for (; j < c; j += 4) {
      if (j + qw < c) {
        int u = col_v[s + j + qw];
        float a0, a1, a2, a3;
        unpk4(*((const uint2*)(h12s + (size_t)u * 128 + 64) + sl), a0, a1, a2, a3);
        av[0] += a0; av[1] += a1; av[2] += a2; av[3] += a3;
      }
    }
  }
#pragma unroll
  for (int k = 0; k < 4; ++k) {
    ac[k] += __shfl_xor(ac[k], 16, 64); ac[k] += __shfl_xor(ac[k], 32, 64);
    av[k] += __shfl_xor(av[k], 16, 64); av[k] += __shfl_xor(av[k], 32, 64);
  }
  const float dc = dis_c[v], dv = dis_v[v];
  float4 bc4 = *(const float4*)(b_corr + sl * 4);
  float4 bv4 = *(const float4*)(b_vendor + sl * 4);
  float oc[4], ov[4];
  oc[0] = dc * ac[0] + bc4.x; oc[1] = dc * ac[1] + bc4.y;
  oc[2] = dc * ac[2] + bc4.z; oc[3] = dc * ac[3] + bc4.w;
  ov[0] = dv * av[0] + bv4.x; ov[1] = dv * av[1] + bv4.y;
  ov[2] = dv * av[2] + bv4.z; ov[3] = dv * av[3] + bv4.w;
  // each feature appears in 4 lanes -> divide wave_sum by 4*64
  float m1 = wave_sum(oc[0] + oc[1] + oc[2] + oc[3]) * (1.f / 256.f);
  float m2 = wave_sum(ov[0] + ov[1] + ov[2] + ov[3]) * (1.f / 256.f);
  float dcv[4], dvv[4], q1 = 0.f, q2 = 0.f;
#pragma unroll
  for (int k = 0; k < 4; ++k) {
    dcv[k] = oc[k] - m1; q1 += dcv[k] * dcv[k];
    dvv[k] = ov[k] - m2; q2 += dvv[k] * dvv[k];
  }
  float rs1 = rsqrtf(wave_sum(q1) * (1.f / 256.f) + 1e-5f);
  float rs2 = rsqrtf(wave_sum(q2) * (1.f / 256.f) + 1e-5f);
  float4 g14 = *(const float4*)(g1 + sl * 4);
  float4 l14 = *(const float4*)(bl1 + sl * 4);
  float4 g24 = *(const float4*)(g2 + sl * 4);
  float4 l24 = *(const float4*)(bl2 + sl * 4);
  float nc[4], nv[4];
  nc[0] = dcv[0] * rs1 * g14.x + l14.x; nc[1] = dcv[1] * rs1 * g14.y + l14.y;
  nc[2] = dcv[2] * rs1 * g14.z + l14.z; nc[3] = dcv[3] * rs1 * g14.w + l14.w;
  nv[0] = dvv[0] * rs2 * g24.x + l24.x; nv[1] = dvv[1] * rs2 * g24.y + l24.y;
  nv[2] = dvv[2] * rs2 * g24.z + l24.z; nv[3] = dvv[3] * rs2 * g24.w + l24.w;
#pragma unroll
  for (int k = 0; k < 4; ++k) {
    nc[k] = (nc[k] > 0.f) ? nc[k] : expm1f(nc[k]);
    nv[k] = (nv[k] > 0.f) ? nv[k] : expm1f(nv[k]);
  }
  if (qw == 0) {
    *(float4*)(h + vb + sl * 4) = make_float4(nc[0], nc[1], nc[2], nc[3]);
  } else if (qw == 1) {
    *(float4*)(h + vb + 64 + sl * 4) = make_float4(nv[0], nv[1], nv[2], nv[3]);
  }
}

// -------------------- fused gather(combined) + bias + LN + ELU + out-projection --------------------
// wave per node; 2 half-waves: each hw's 32 lanes read one neighbor's 256B
// bf16 row as uint2 (2 neighbors per issue, 4 in flight with unroll-2).
__global__ __launch_bounds__(256) void gather_ln3_out(
    const unsigned short* __restrict__ h3s,
    const int* __restrict__ row_c, const int* __restrict__ cnt_c, const int* __restrict__ col_c,
    const int* __restrict__ row_v, const int* __restrict__ cnt_v, const int* __restrict__ col_v,
    const float* __restrict__ dis_cb,
    const float* __restrict__ b_ref, const float* __restrict__ g3, const float* __restrict__ bl3,
    const float* __restrict__ W_out, const float* __restrict__ b_out,
    float* __restrict__ out, int n) {
  const int lane = threadIdx.x & 63;
  const int v = blockIdx.x * 4 + (threadIdx.x >> 6);
  if (v >= n) return;
  const int hw = lane >> 5;   // 0..1
  const int sl = lane & 31;   // features 4sl..4sl+3 of 128
  const size_t vb = (size_t)v * 128;
  float a[4] = {0.f, 0.f, 0.f, 0.f};
  if (hw == 0) {  // self loop counted once
    unpk4(*((const uint2*)(h3s + vb) + sl), a[0], a[1], a[2], a[3]);
  }
  {
    int s = row_c[v], c = cnt_c[v], j = 0;
    for (; j + 4 <= c; j += 4) {
      int u0 = col_c[s + j + hw], u1 = col_c[s + j + 2 + hw];
      uint2 p0 = *((const uint2*)(h3s + (size_t)u0 * 128) + sl);
      uint2 p1 = *((const uint2*)(h3s + (size_t)u1 * 128) + sl);
      float a0, a1, a2, a3, b0, b1, b2, b3;
      unpk4(p0, a0, a1, a2, a3); unpk4(p1, b0, b1, b2, b3);
      a[0] += a0 + b0; a[1] += a1 + b1; a[2] += a2 + b2; a[3] += a3 + b3;
    }
    for (; j < c; j += 2) {
      if (j + hw < c) {
        int u = col_c[s + j + hw];
        float a0, a1, a2, a3;
        unpk4(*((const uint2*)(h3s + (size_t)u * 128) + sl), a0, a1, a2, a3);
        a[0] += a0; a[1] += a1; a[2] += a2; a[3] += a3;
      }
    }
  }
  {
    int s = row_v[v], c = cnt_v[v], j = 0;
    for (; j + 4 <= c; j += 4) {
      int u0 = col_v[s + j + hw], u1 = col_v[s + j + 2 + hw];
      uint2 p0 = *((const uint2*)(h3s + (size_t)u0 * 128) + sl);
      uint2 p1 = *((const uint2*)(h3s + (size_t)u1 * 128) + sl);
      float a0, a1, a2, a3, b0, b1, b2, b3;
      unpk4(p0, a0, a1, a2, a3); unpk4(p1, b0, b1, b2, b3);
      a[0] += a0 + b0; a[1] += a1 + b1; a[2] += a2 + b2; a[3] += a3 + b3;
    }
    for (; j < c; j += 2) {
      if (j + hw < c) {
        int u = col_v[s + j + hw];
        float a0, a1, a2, a3;
        unpk4(*((const uint2*)(h3s + (size_t)u * 128) + sl), a0, a1, a2, a3);
        a[0] += a0; a[1] += a1; a[2] += a2; a[3] += a3;
      }
    }
  }
#pragma unroll
  for (int k = 0; k < 4; ++k) a[k] += __shfl_xor(a[k], 32, 64);
  const float sc = dis_cb[v];
  float4 br4 = *(const float4*)(b_ref + sl * 4);
  float o[4];
  o[0] = sc * a[0] + br4.x; o[1] = sc * a[1] + br4.y;
  o[2] = sc * a[2] + br4.z; o[3] = sc * a[3] + br4.w;
  // each feature appears in 2 lanes -> divide wave_sum by 2*128
  float m = wave_sum(o[0] + o[1] + o[2] + o[3]) * (1.f / 256.f);
  float d[4], q = 0.f;
#pragma unroll
  for (int k = 0; k < 4; ++k) { d[k] = o[k] - m; q += d[k] * d[k]; }
  float rs = rsqrtf(wave_sum(q) * (1.f / 256.f) + 1e-5f);
  float4 g34 = *(const float4*)(g3 + sl * 4);
  float4 l34 = *(const float4*)(bl3 + sl * 4);
  float4 w4  = *(const float4*)(W_out + sl * 4);
  float e0 = d[0] * rs * g34.x + l34.x;
  float e1 = d[1] * rs * g34.y + l34.y;
  float e2 = d[2] * rs * g34.z + l34.z;
  float e3 = d[3] * rs * g34.w + l34.w;
  e0 = (e0 > 0.f) ? e0 : expm1f(e0);
  e1 = (e1 > 0.f) ? e1 : expm1f(e1);
  e2 = (e2 > 0.f) ? e2 : expm1f(e2);
  e3 = (e3 > 0.f) ? e3 : expm1f(e3);
  float dot = wave_sum(e0 * w4.x + e1 * w4.y + e2 * w4.z + e3 * w4.w) * 0.5f;
  if (lane == 0) out[v] = dot + b_out[0];
}

// -------------------- launch --------------------
extern "C" void kernel_launch(void* const* d_in, const int* in_sizes, int n_in,
                              void* d_out, int out_size, void* d_ws, size_t ws_size,
                              hipStream_t stream) {
  const float* x        = (const float*)d_in[0];
  const int* eic        = (const int*)d_in[1];
  const int* eiv        = (const int*)d_in[2];
  const float* xl       = (const float*)d_in[3];
  const float* W_corr   = (const float*)d_in[4];
  const float* b_corr   = (const float*)d_in[5];
  const float* g_ln_c   = (const float*)d_in[6];
  const float* b_ln_c   = (const float*)d_in[7];
  const float* W_vendor = (const float*)d_in[8];
  const float* b_vendor = (const float*)d_in[9];
  const float* g_ln_v   = (const float*)d_in[10];
  const float* b_ln_v   = (const float*)d_in[11];
  const float* W_refine = (const float*)d_in[12];
  const float* b_refine = (const float*)d_in[13];
  const float* g_ln_r   = (const float*)d_in[14];
  const float* b_ln_r   = (const float*)d_in[15];
  const float* W_out    = (const float*)d_in[16];
  const float* b_out    = (const float*)d_in[17];
  float* out = (float*)d_out;

  const int N = in_sizes[0] / 128;
  const int E = in_sizes[1] / 2;

  // layout (dwords unless noted):
  // [cnt_c N][cnt_v N][row_c N][row_v N][col_c E][col_v E]
  // [dis_c N][dis_v N][dis_cb N][h12s 128N bf16 = 64N dwords][h 128N f32]
  // rank_c/rank_v (2E ints = 6.4MB) alias h12s (12.8MB, dead until GEMMs).
  int* iw = (int*)d_ws;
  int* cnt_c = iw;
  int* cnt_v = iw + N;
  int* row_c = iw + 2 * (size_t)N;
  int* row_v = iw + 3 * (size_t)N;
  int* col_c = iw + 4 * (size_t)N;
  int* col_v = iw + 4 * (size_t)N + E;
  float* fw = (float*)d_ws;
  float* dis_c  = fw + 4 * (size_t)N + 2 * (size_t)E;
  float* dis_v  = dis_c + N;
  float* dis_cb = dis_v + N;
  unsigned short* h12s = (unsigned short*)(dis_cb + N);  // 128N bf16 (reused as h3s)
  float* h = (float*)(h12s + (size_t)N * 128);           // 128N f32
  int* rank_c = (int*)h12s;                              // aliases h12s during prep
  int* rank_v = rank_c + E;

  hipMemsetAsync(d_ws, 0, (size_t)2 * N * sizeof(int), stream);

  int eb = (E + 255) / 256;
  count_kernel<<<eb, 256, 0, stream>>>(eic, eiv, cnt_c, cnt_v, rank_c, rank_v, E);
  scan_kernel<<<2, 1024, 0, stream>>>(cnt_c, row_c, cnt_v, row_v, N);
  dis_kernel<<<(N + 255) / 256, 256, 0, stream>>>(cnt_c, cnt_v, dis_c, dis_v, dis_cb, N);
  fill_kernel<<<eb, 256, 0, stream>>>(eic, eiv, rank_c, rank_v, row_c, row_v, col_c, col_v, E);

  int gb = (N + 63) / 64;
  gemm_n64<1><<<gb, 256, 0, stream>>>(x, nullptr, W_corr, 64, 0, dis_c, h12s, 0, N);
  gemm_n64<2><<<gb, 256, 0, stream>>>(x, xl, W_vendor, 64, 0, dis_v, h12s, 64, N);

  int nb4 = (N + 3) / 4;
  gather_ln12<<<nb4, 256, 0, stream>>>(h12s, row_c, cnt_c, col_c, row_v, cnt_v, col_v,
                                       dis_c, dis_v, b_corr, g_ln_c, b_ln_c,
                                       b_vendor, g_ln_v, b_ln_v, h, N);

  unsigned short* h3s = h12s;  // h12s dead after gather_ln12
  gemm_n64<1><<<gb, 256, 0, stream>>>(h, nullptr, W_refine, 128, 0, dis_cb, h3s, 0, N);
  gemm_n64<1><<<gb, 256, 0, stream>>>(h, nullptr, W_refine, 128, 64, dis_cb, h3s, 64, N);

  gather_ln3_out<<<nb4, 256, 0, stream>>>(h3s, row_c, cnt_c, col_c, row_v, cnt_v, col_v,
                                          dis_cb, b_refine, g_ln_r, b_ln_r,
                                          W_out, b_out, out, N);
}